// Round 5
// baseline (1226.629 us; speedup 1.0000x reference)
//
#include <hip/hip_runtime.h>
#include <math.h>

typedef unsigned short u16;
typedef unsigned int   u32;

#define E_EDGES 100000
#define NNODES  5000
#define INV_SQRT3 0.57735026918962576f
#define INV_AVG   0.05f

typedef short bf16x8 __attribute__((ext_vector_type(8)));
typedef float f32x4  __attribute__((ext_vector_type(4)));
typedef int   i32x4  __attribute__((ext_vector_type(4)));

__device__ __forceinline__ float us2f(u16 u) {
    union { float f; u32 i; } c; c.i = ((u32)u) << 16; return c.f;
}
__device__ __forceinline__ u16 f2us(float f) {
    union { float f; u32 i; } c; c.f = f;
    u32 x = c.i;
    x += 0x7fffu + ((x >> 16) & 1u);   // round-to-nearest-even bf16
    return (u16)(x >> 16);
}
__device__ __forceinline__ float siluf(float x) { return x / (1.f + expf(-x)); }

// ---------------------------------------------------------------------------
// MFMA GEMM, 4 waves, tile 128x128: Y = epi( concat(X1,X2) @ (W_hi+W_lo) )
// W stored transposed [n][k], n padded to >= grid cols, k padded to mult 32.
// Wave w: rows (w>>1)*64.., cols (w&1)*64..  (4x4 frags of 16x16).
// LDS granule-major: byte offset g*2048 + row*16 (g = k-granule 0..3).
// STAGING: reg-staged, coalesced (R4: 4 lanes = one row's 64B k-slice).
// R5: DEPTH-2 register prefetch. At iter k0: issue loads for k0+64 (nx2),
// compute lds[cur], ds_write tile k0+32 (nx1, loaded a FULL iteration ago)
// into lds[cur^1]. Load->write cover grows ~0.5 iter -> ~1.5 iter (~1200cyc),
// covering cold-HBM latency (~900cyc). Compiler emits counted vmcnt (nx2's
// loads stay in flight across the barrier) -- never a full drain in-loop.
// EPI: 0 none, 1 silu, 2 cut-scale, 3 residual blend (reads old Y, cut, resp)
//      4 scalar-out fusion: OUTF[row*512+col] = acc * bf16(F[row*128+col])
//      5 vector-out fusion: row=e*3+c, col=o*64+v ->
//                           OUTF[e*512 + 128 + o*192 + v*3 + c] = acc
// ---------------------------------------------------------------------------
template <int EPI>
__global__ __launch_bounds__(256) void mgemm2_k(
    const u16* __restrict__ X1, int ldx1, int K1,
    const u16* __restrict__ X2, int ldx2, int K2,
    const u16* __restrict__ Wh, const u16* __restrict__ Wl, int ldk,
    u16* __restrict__ Y, int ldy, int M, int N,
    const float* __restrict__ cut, const float* __restrict__ resp,
    const u16* __restrict__ F, float* __restrict__ OUTF)
{
    __shared__ short lA[2][4096];    // 16KB : g*2048B + row*16B
    __shared__ short lBh[2][4096];   // 16KB
    __shared__ short lBl[2][4096];   // 16KB
    const int lane = threadIdx.x & 63;
    const int w    = threadIdx.x >> 6;    // wave 0..3
    const int q    = lane >> 4;           // k-granule (read side)
    const int r16  = lane & 15;
    const int sr   = lane >> 2;           // staging: row-in-group 0..15
    const int sg   = lane & 3;            // staging: k-granule 0..3
    const int m0 = blockIdx.x * 128;
    const int n0 = blockIdx.y * 128;
    const int wr0 = (w >> 1) * 64;        // wave row base in tile
    const int wc0 = (w & 1) * 64;         // wave col base in tile
    const int Kt = K1 + K2;
    const int j0 = w * 2, j1 = w * 2 + 1; // this wave's 16-row chunks

    struct Stage { i32x4 a0, a1, b0h, b1h, b0l, b1l; };
    auto load_tile = [&](int k0) -> Stage {
        const u16* xs; int ldx, kb;
        if (k0 < K1) { xs = X1; ldx = ldx1; kb = k0; }
        else         { xs = X2; ldx = ldx2; kb = k0 - K1; }
        Stage s;
        int row0 = m0 + j0 * 16 + sr; row0 = row0 < M ? row0 : M - 1;
        int row1 = m0 + j1 * 16 + sr; row1 = row1 < M ? row1 : M - 1;
        s.a0 = *(const i32x4*)(xs + (size_t)row0 * ldx + kb + sg * 8);
        s.a1 = *(const i32x4*)(xs + (size_t)row1 * ldx + kb + sg * 8);
        const size_t wo0 = (size_t)(n0 + j0 * 16 + sr) * ldk + k0 + sg * 8;
        const size_t wo1 = (size_t)(n0 + j1 * 16 + sr) * ldk + k0 + sg * 8;
        s.b0h = *(const i32x4*)(Wh + wo0);
        s.b1h = *(const i32x4*)(Wh + wo1);
        s.b0l = *(const i32x4*)(Wl + wo0);
        s.b1l = *(const i32x4*)(Wl + wo1);
        return s;
    };
    auto write_tile = [&](const Stage& s, int buf) {
        char* A  = (char*)&lA[buf][0];
        char* Bh = (char*)&lBh[buf][0];
        char* Bl = (char*)&lBl[buf][0];
        const int o0 = sg * 2048 + (j0 * 16 + sr) * 16;
        const int o1 = sg * 2048 + (j1 * 16 + sr) * 16;
        *(i32x4*)(A  + o0) = s.a0;  *(i32x4*)(A  + o1) = s.a1;
        *(i32x4*)(Bh + o0) = s.b0h; *(i32x4*)(Bh + o1) = s.b1h;
        *(i32x4*)(Bl + o0) = s.b0l; *(i32x4*)(Bl + o1) = s.b1l;
    };

    f32x4 acc[4][4];
#pragma unroll
    for (int i = 0; i < 4; ++i)
#pragma unroll
        for (int j = 0; j < 4; ++j) acc[i][j] = (f32x4){0.f, 0.f, 0.f, 0.f};

    {
        Stage s0 = load_tile(0);
        write_tile(s0, 0);
    }
    Stage nx1;                     // tile k0+32 (written NEXT iteration)
    if (32 < Kt) nx1 = load_tile(32);
    __syncthreads();
    int cur = 0;
    for (int k0 = 0; k0 < Kt; k0 += 32) {
        const bool more2 = (k0 + 64 < Kt);
        const bool more1 = (k0 + 32 < Kt);
        Stage nx2;
        if (more2) nx2 = load_tile(k0 + 64);   // 2-deep prefetch issue
        bf16x8 a[4], bh[4], bl[4];
#pragma unroll
        for (int rt = 0; rt < 4; ++rt)
            a[rt] = *(const bf16x8*)&lA[cur][q * 1024 + (wr0 + rt * 16 + r16) * 8];
#pragma unroll
        for (int ct = 0; ct < 4; ++ct) {
            bh[ct] = *(const bf16x8*)&lBh[cur][q * 1024 + (wc0 + ct * 16 + r16) * 8];
            bl[ct] = *(const bf16x8*)&lBl[cur][q * 1024 + (wc0 + ct * 16 + r16) * 8];
        }
#pragma unroll
        for (int rt = 0; rt < 4; ++rt)
#pragma unroll
            for (int ct = 0; ct < 4; ++ct) {
                acc[rt][ct] = __builtin_amdgcn_mfma_f32_16x16x32_bf16(a[rt], bh[ct], acc[rt][ct], 0, 0, 0);
                acc[rt][ct] = __builtin_amdgcn_mfma_f32_16x16x32_bf16(a[rt], bl[ct], acc[rt][ct], 0, 0, 0);
            }
        if (more1) write_tile(nx1, cur ^ 1);   // counted vmcnt: only nx1's loads
        __syncthreads();
        nx1 = nx2;
        cur ^= 1;
    }
    // ---- epilogue ----
    float c1 = 0.f, c2a = 0.f;
    if (EPI == 3) {
        float aa = 1.f / (1.f + expf(-resp[1]));
        c1 = sqrtf(1.f - aa);
        c2a = sqrtf(aa);
    }
#pragma unroll
    for (int rt = 0; rt < 4; ++rt) {
#pragma unroll
        for (int r = 0; r < 4; ++r) {
            const int row = m0 + wr0 + rt * 16 + q * 4 + r;
            if (row < M) {
                float sc = 1.f;
                if (EPI == 2) sc = cut[row];
                float c2 = 0.f;
                if (EPI == 3) c2 = c2a * cut[row];
                int e3 = 0, cc = 0;
                if (EPI == 5) { e3 = row / 3; cc = row - e3 * 3; }
#pragma unroll
                for (int ct = 0; ct < 4; ++ct) {
                    const int col = n0 + wc0 + ct * 16 + r16;
                    if (col < N) {
                        float v = acc[rt][ct][r];
                        if (EPI == 1) v = siluf(v);
                        if (EPI == 2) v *= sc;
                        if (EPI == 3) v = c1 * us2f(Y[(size_t)row * ldy + col]) + c2 * v;
                        if (EPI == 4) {
                            OUTF[(size_t)row * 512 + col] = v * us2f(F[(size_t)row * 128 + col]);
                        } else if (EPI == 5) {
                            OUTF[(size_t)e3 * 512 + 128 + (col >> 6) * 192 + (col & 63) * 3 + cc] = v;
                        } else {
                            Y[(size_t)row * ldy + col] = f2us(v);
                        }
                    }
                }
            }
        }
    }
}

// ---------------------------------------------------------------------------
// 2-wave 128x64 variant (N=64 lin0 GEMMs) — same depth-2 prefetch pipeline.
// ---------------------------------------------------------------------------
__global__ __launch_bounds__(128) void mgemm_k(
    const u16* __restrict__ X1, int ldx1, int K1,
    const u16* __restrict__ Wh, const u16* __restrict__ Wl, int ldk,
    u16* __restrict__ Y, int ldy, int M)
{
    __shared__ short lA[2][4096];
    __shared__ short lBh[2][2048];
    __shared__ short lBl[2][2048];
    const int lane = threadIdx.x & 63;
    const int w    = threadIdx.x >> 6;
    const int q    = lane >> 4;
    const int r16  = lane & 15;
    const int sr   = lane >> 2;
    const int sg   = lane & 3;
    const int m0 = blockIdx.x * 128;
    const int n0 = blockIdx.y * 64;
    const int Kt = K1;

    struct Stage { i32x4 a[4]; i32x4 bh[2]; i32x4 bl[2]; };
    auto load_tile = [&](int k0) -> Stage {
        Stage s;
#pragma unroll
        for (int i = 0; i < 4; ++i) {
            const int j = w * 4 + i;
            int row = m0 + j * 16 + sr; row = row < M ? row : M - 1;
            s.a[i] = *(const i32x4*)(X1 + (size_t)row * ldx1 + k0 + sg * 8);
        }
#pragma unroll
        for (int i = 0; i < 2; ++i) {
            const int j = w * 2 + i;
            const size_t wo = (size_t)(n0 + j * 16 + sr) * ldk + k0 + sg * 8;
            s.bh[i] = *(const i32x4*)(Wh + wo);
            s.bl[i] = *(const i32x4*)(Wl + wo);
        }
        return s;
    };
    auto write_tile = [&](const Stage& s, int buf) {
        char* A  = (char*)&lA[buf][0];
        char* Bh = (char*)&lBh[buf][0];
        char* Bl = (char*)&lBl[buf][0];
#pragma unroll
        for (int i = 0; i < 4; ++i) {
            const int j = w * 4 + i;
            *(i32x4*)(A + sg * 2048 + (j * 16 + sr) * 16) = s.a[i];
        }
#pragma unroll
        for (int i = 0; i < 2; ++i) {
            const int j = w * 2 + i;
            const int o = sg * 1024 + (j * 16 + sr) * 16;
            *(i32x4*)(Bh + o) = s.bh[i];
            *(i32x4*)(Bl + o) = s.bl[i];
        }
    };

    f32x4 acc[4][4];
#pragma unroll
    for (int i = 0; i < 4; ++i)
#pragma unroll
        for (int j = 0; j < 4; ++j) acc[i][j] = (f32x4){0.f, 0.f, 0.f, 0.f};

    {
        Stage s0 = load_tile(0);
        write_tile(s0, 0);
    }
    Stage nx1;
    if (32 < Kt) nx1 = load_tile(32);
    __syncthreads();
    int cur = 0;
    for (int k0 = 0; k0 < Kt; k0 += 32) {
        const bool more2 = (k0 + 64 < Kt);
        const bool more1 = (k0 + 32 < Kt);
        Stage nx2;
        if (more2) nx2 = load_tile(k0 + 64);
        bf16x8 a[4], bh[4], bl[4];
#pragma unroll
        for (int rt = 0; rt < 4; ++rt)
            a[rt] = *(const bf16x8*)&lA[cur][q * 1024 + (w * 64 + rt * 16 + r16) * 8];
#pragma unroll
        for (int ct = 0; ct < 4; ++ct) {
            bh[ct] = *(const bf16x8*)&lBh[cur][q * 512 + (ct * 16 + r16) * 8];
            bl[ct] = *(const bf16x8*)&lBl[cur][q * 512 + (ct * 16 + r16) * 8];
        }
#pragma unroll
        for (int rt = 0; rt < 4; ++rt)
#pragma unroll
            for (int ct = 0; ct < 4; ++ct) {
                acc[rt][ct] = __builtin_amdgcn_mfma_f32_16x16x32_bf16(a[rt], bh[ct], acc[rt][ct], 0, 0, 0);
                acc[rt][ct] = __builtin_amdgcn_mfma_f32_16x16x32_bf16(a[rt], bl[ct], acc[rt][ct], 0, 0, 0);
            }
        if (more1) write_tile(nx1, cur ^ 1);
        __syncthreads();
        nx1 = nx2;
        cur ^= 1;
    }
#pragma unroll
    for (int rt = 0; rt < 4; ++rt) {
#pragma unroll
        for (int r = 0; r < 4; ++r) {
            const int row = m0 + w * 64 + rt * 16 + q * 4 + r;
            if (row < M) {
#pragma unroll
                for (int ct = 0; ct < 4; ++ct)
                    Y[(size_t)row * ldy + n0 + ct * 16 + r16] = f2us(acc[rt][ct][r]);
            }
        }
    }
}

// ---------------------------------------------------------------------------
// Weight prep: f32 W (Ksrc x Nsrc row-major) -> bf16 hi/lo transposed [n][k],
// padded to Npad x Kpad with zeros.
// MODE 0: standard. MODE 1: lin1 (2,2,64,64) [i][o][u][v], k=i*64+u, n=o*64+v.
// ---------------------------------------------------------------------------
template <int MODE>
__global__ __launch_bounds__(256) void split_w_k(
    const float* __restrict__ src, u16* __restrict__ hi, u16* __restrict__ lo,
    int Ksrc, int Nsrc, int Kpad, int Npad)
{
    int idx = blockIdx.x * 256 + threadIdx.x;
    if (idx >= Npad * Kpad) return;
    int n = idx / Kpad, k = idx - n * Kpad;
    float wv = 0.f;
    if (k < Ksrc && n < Nsrc) {
        if (MODE == 0) wv = src[(size_t)k * Nsrc + n];
        else           wv = src[(k >> 6) * 8192 + (n >> 6) * 4096 + (k & 63) * 64 + (n & 63)];
    }
    u16 h = f2us(wv);
    hi[idx] = h;
    lo[idx] = f2us(wv - us2f(h));
}

// ---------------------------------------------------------------------------
// prep: X0 = [node[center] | node[neigh] | radial | 0pad] (E x 160 bf16), cut
// ---------------------------------------------------------------------------
__global__ __launch_bounds__(256) void prep_edges_k(
    const float* __restrict__ na, const float* __restrict__ radial,
    const float* __restrict__ lengths, const int* __restrict__ eidx,
    u16* __restrict__ X0, float* __restrict__ cut)
{
    int idx = blockIdx.x * 256 + threadIdx.x;
    if (idx >= E_EDGES * 160) return;
    int e = idx / 160;
    int k = idx - e * 160;
    float v = 0.f;
    if (k < 64)       v = na[(size_t)eidx[e] * 64 + k];
    else if (k < 128) v = na[(size_t)eidx[E_EDGES + e] * 64 + (k - 64)];
    else if (k < 136) v = radial[(size_t)e * 8 + (k - 128)];
    X0[idx] = f2us(v);
    if (k == 136) {
        float x = lengths[e] * 0.2f;           // r / R_MAX
        float x3 = x * x * x;
        float x6 = x3 * x3, x7 = x6 * x, x8 = x7 * x;
        float o = 1.f - 28.f * x6 + 48.f * x7 - 21.f * x8;
        cut[e] = (x < 1.f) ? o : 0.f;
    }
}

// ---------------------------------------------------------------------------
// counting sort of edges by center node
// ---------------------------------------------------------------------------
__global__ __launch_bounds__(256) void hist_k(const int* __restrict__ eidx, int* __restrict__ cnt)
{
    int e = blockIdx.x * 256 + threadIdx.x;
    if (e < E_EDGES) atomicAdd(&cnt[eidx[e]], 1);
}

__global__ __launch_bounds__(256) void scan_k(const int* __restrict__ cnt, int* __restrict__ offs)
{
    __shared__ int buf[256];
    __shared__ int base;
    if (threadIdx.x == 0) base = 0;
    __syncthreads();
    for (int start = 0; start < NNODES; start += 256) {
        int i = start + threadIdx.x;
        int v = (i < NNODES) ? cnt[i] : 0;
        buf[threadIdx.x] = v;
        __syncthreads();
        for (int d = 1; d < 256; d <<= 1) {
            int t = (threadIdx.x >= d) ? buf[threadIdx.x - d] : 0;
            __syncthreads();
            buf[threadIdx.x] += t;
            __syncthreads();
        }
        if (i < NNODES) offs[i] = base + buf[threadIdx.x] - v;
        __syncthreads();
        if (threadIdx.x == 255) base += buf[255];
        __syncthreads();
    }
}

__global__ __launch_bounds__(256) void scatter_k(
    const int* __restrict__ eidx, const int* __restrict__ offs,
    int* __restrict__ cur, int* __restrict__ perm)
{
    int e = blockIdx.x * 256 + threadIdx.x;
    if (e >= E_EDGES) return;
    int n = eidx[e];
    int p = atomicAdd(&cur[n], 1);
    perm[offs[n] + p] = e;
}

// ---------------------------------------------------------------------------
// per-node env segment-sum + envlin (replaces atomics + nodelin)
// LD = wall row stride (320 stage B, 192 stage C); env weights at cols [0,128)
// ---------------------------------------------------------------------------
template <int LD>
__global__ __launch_bounds__(64) void envsum_k(
    const u16* __restrict__ wall, const float* __restrict__ ang,
    const int* __restrict__ perm, const int* __restrict__ offs, const int* __restrict__ cnt,
    const float* __restrict__ envlin,
    float* __restrict__ ns_e, float* __restrict__ nv_e)
{
    const int n = blockIdx.x, lane = threadIdx.x;
    const int s = offs[n], c = cnt[n];
    float a0 = 0.f, a1 = 0.f, a2 = 0.f, a3 = 0.f;
    for (int i = 0; i < c; ++i) {
        int e = perm[s + i];
        u32 pw = *(const u32*)(wall + (size_t)e * LD + 2 * lane);
        float we0 = us2f((u16)(pw & 0xffffu)), we1 = us2f((u16)(pw >> 16));
        float4 sh = *(const float4*)(ang + (size_t)e * 4);
        a0 = fmaf(we0, sh.x, a0);
        a1 = fmaf(we1, sh.y, a1);
        a2 = fmaf(we1, sh.z, a2);
        a3 = fmaf(we1, sh.w, a3);
    }
    __shared__ float ss[64], sv0[64], sv1[64], sv2[64];
    ss[lane] = a0; sv0[lane] = a1; sv1[lane] = a2; sv2[lane] = a3;
    __syncthreads();
    const float* L0 = envlin;
    const float* L1 = envlin + 4096;
    float b0 = 0.f, b1 = 0.f, b2 = 0.f, b3 = 0.f;
#pragma unroll 8
    for (int u = 0; u < 64; ++u) {
        float l0 = L0[u * 64 + lane], l1 = L1[u * 64 + lane];
        b0 = fmaf(ss[u],  l0, b0);
        b1 = fmaf(sv0[u], l1, b1);
        b2 = fmaf(sv1[u], l1, b2);
        b3 = fmaf(sv2[u], l1, b3);
    }
    ns_e[n * 64 + lane]           = b0 * INV_AVG;
    nv_e[n * 192 + lane]          = b1 * INV_AVG;
    nv_e[n * 192 + 64 + lane]     = b2 * INV_AVG;
    nv_e[n * 192 + 128 + lane]    = b3 * INV_AVG;
}

// ---------------------------------------------------------------------------
// stage-B fused gate + tensor product (reads wall directly, no fsg/fvg)
// ---------------------------------------------------------------------------
__global__ __launch_bounds__(256) void tp0f_k(
    const u16* __restrict__ wall, const float* __restrict__ ang,
    const float* __restrict__ ns_e, const float* __restrict__ nv_e,
    const int* __restrict__ eidx, u16* __restrict__ ts, u16* __restrict__ tv)
{
    int idx = blockIdx.x * 256 + threadIdx.x;
    if (idx >= E_EDGES * 64) return;
    int e = idx >> 6, u = idx & 63;
    int ce = eidx[e];
    const u16* wr = wall + (size_t)e * 320;
    float g   = us2f(wr[128 + u]);
    u32 pw = *(const u32*)&wr[192 + 2 * u];
    float wf0 = us2f((u16)(pw & 0xffffu)), wf1 = us2f((u16)(pw >> 16));
    float4 sh = *(const float4*)(ang + (size_t)e * 4);
    float f  = wf0 * sh.x * g;
    float b0 = wf1 * sh.y * g;
    float b1 = wf1 * sh.z * g;
    float b2 = wf1 * sh.w * g;
    float ns = ns_e[ce * 64 + u];
    float n0 = nv_e[ce * 192 + u], n1 = nv_e[ce * 192 + 64 + u], n2 = nv_e[ce * 192 + 128 + u];
    ts[(size_t)e * 128 + u]      = f2us(f * ns);
    ts[(size_t)e * 128 + 64 + u] = f2us((b0 * n0 + b1 * n1 + b2 * n2) * INV_SQRT3);
    size_t tb = (size_t)e * 384;
    tv[tb + u]             = f2us(f * n0 * INV_SQRT3);
    tv[tb + 128 + u]       = f2us(f * n1 * INV_SQRT3);
    tv[tb + 256 + u]       = f2us(f * n2 * INV_SQRT3);
    tv[tb + 64 + u]        = f2us(b0 * ns * INV_SQRT3);
    tv[tb + 128 + 64 + u]  = f2us(b1 * ns * INV_SQRT3);
    tv[tb + 256 + 64 + u]  = f2us(b2 * ns * INV_SQRT3);
}

// ---------------------------------------------------------------------------
// stage-C fused gate + tensor product (gates lin0 outputs fs1/fv1 on the fly)
// ---------------------------------------------------------------------------
__global__ __launch_bounds__(256) void tp1f_k(
    const u16* __restrict__ fs1, const u16* __restrict__ fv1,
    const u16* __restrict__ wall,
    const float* __restrict__ ns_e, const float* __restrict__ nv_e,
    const int* __restrict__ eidx, u16* __restrict__ ts, u16* __restrict__ tv)
{
    int idx = blockIdx.x * 256 + threadIdx.x;
    if (idx >= E_EDGES * 64) return;
    int e = idx >> 6, u = idx & 63;
    int ce = eidx[e];
    float g = us2f(wall[(size_t)e * 192 + 128 + u]);
    float f  = us2f(fs1[(size_t)e * 64 + u]) * g;
    float b0 = us2f(fv1[((size_t)e * 3 + 0) * 64 + u]) * g;
    float b1 = us2f(fv1[((size_t)e * 3 + 1) * 64 + u]) * g;
    float b2 = us2f(fv1[((size_t)e * 3 + 2) * 64 + u]) * g;
    float ns = ns_e[ce * 64 + u];
    float n0 = nv_e[ce * 192 + u], n1 = nv_e[ce * 192 + 64 + u], n2 = nv_e[ce * 192 + 128 + u];
    ts[(size_t)e * 128 + u]      = f2us(f * ns);
    ts[(size_t)e * 128 + 64 + u] = f2us((b0 * n0 + b1 * n1 + b2 * n2) * INV_SQRT3);
    size_t tb = (size_t)e * 384;
    tv[tb + u]             = f2us(f * n0 * INV_SQRT3);
    tv[tb + 128 + u]       = f2us(f * n1 * INV_SQRT3);
    tv[tb + 256 + u]       = f2us(f * n2 * INV_SQRT3);
    tv[tb + 64 + u]        = f2us(b0 * ns * INV_SQRT3);
    tv[tb + 128 + 64 + u]  = f2us(b1 * ns * INV_SQRT3);
    tv[tb + 256 + 64 + u]  = f2us(b2 * ns * INV_SQRT3);
}

// ---------------------------------------------------------------------------
static void mgemm2(hipStream_t s, int epi,
                   const u16* X1, int ldx1, int K1,
                   const u16* X2, int ldx2, int K2,
                   const u16* Wh, const u16* Wl, int ldk,
                   u16* Y, int ldy, int M, int N,
                   const float* cut, const float* resp,
                   const u16* F, float* OUTF)
{
    dim3 grid((M + 127) / 128, (N + 127) / 128);
    dim3 block(256);
    if (epi == 0)      mgemm2_k<0><<<grid, block, 0, s>>>(X1, ldx1, K1, X2, ldx2, K2, Wh, Wl, ldk, Y, ldy, M, N, cut, resp, F, OUTF);
    else if (epi == 1) mgemm2_k<1><<<grid, block, 0, s>>>(X1, ldx1, K1, X2, ldx2, K2, Wh, Wl, ldk, Y, ldy, M, N, cut, resp, F, OUTF);
    else if (epi == 2) mgemm2_k<2><<<grid, block, 0, s>>>(X1, ldx1, K1, X2, ldx2, K2, Wh, Wl, ldk, Y, ldy, M, N, cut, resp, F, OUTF);
    else if (epi == 3) mgemm2_k<3><<<grid, block, 0, s>>>(X1, ldx1, K1, X2, ldx2, K2, Wh, Wl, ldk, Y, ldy, M, N, cut, resp, F, OUTF);
    else if (epi == 4) mgemm2_k<4><<<grid, block, 0, s>>>(X1, ldx1, K1, X2, ldx2, K2, Wh, Wl, ldk, Y, ldy, M, N, cut, resp, F, OUTF);
    else               mgemm2_k<5><<<grid, block, 0, s>>>(X1, ldx1, K1, X2, ldx2, K2, Wh, Wl, ldk, Y, ldy, M, N, cut, resp, F, OUTF);
}

static void split_w(hipStream_t s, int mode, const float* src, u16* hi, u16* lo,
                    int Ksrc, int Nsrc, int Kpad, int Npad)
{
    int n = Npad * Kpad;
    dim3 grid((n + 255) / 256), block(256);
    if (mode == 0) split_w_k<0><<<grid, block, 0, s>>>(src, hi, lo, Ksrc, Nsrc, Kpad, Npad);
    else           split_w_k<1><<<grid, block, 0, s>>>(src, hi, lo, Ksrc, Nsrc, Kpad, Npad);
}

extern "C" void kernel_launch(void* const* d_in, const int* in_sizes, int n_in,
                              void* d_out, int out_size, void* d_ws, size_t ws_size,
                              hipStream_t stream)
{
    const float* node_attrs = (const float*)d_in[0];
    const float* radial     = (const float*)d_in[1];
    const float* ang        = (const float*)d_in[2];
    const float* lengths    = (const float*)d_in[3];
    const int*   eidx       = (const int*)d_in[4];
    const float* tb_w0      = (const float*)d_in[5];
    const float* tb_w1      = (const float*)d_in[6];
    const float* tb_w2      = (const float*)d_in[7];
    const float* lat1_w0    = (const float*)d_in[8];
    const float* lat1_w1    = (const float*)d_in[9];
    const float* env0_w     = (const float*)d_in[10];
    const float* env1_w     = (const float*)d_in[11];
    const float* envlin0    = (const float*)d_in[12];
    const float* envlin1    = (const float*)d_in[13];
    const float* lin0_sw    = (const float*)d_in[14];
    const float* lin0_vw    = (const float*)d_in[15];
    const float* lin1_sw    = (const float*)d_in[16];
    const float* lin1_vw    = (const float*)d_in[17];
    const float* fin_w0     = (const float*)d_in[18];
    const float* fin_w1     = (const float*)d_in[19];
    const float* res_p      = (const float*)d_in[20];

    const size_t E = E_EDGES;
    unsigned char* ws = (unsigned char*)d_ws;
    size_t off = 0;
    auto take = [&](size_t n) -> void* {
        void* p = ws + off;
        off += (n + 255) & ~(size_t)255;
        return p;
    };
    u16*  X0   = (u16*)take(E * 160 * 2);
    float* cut = (float*)take(E * 4);
    u16*  hA   = (u16*)take(E * 256 * 2);
    u16*  hB   = (u16*)take(E * 256 * 2);
    u16*  lat  = (u16*)take(E * 256 * 2);
    u16*  wall = (u16*)take(E * 320 * 2);   // reused for w_all1 (E x 192)
    u16*  ts   = (u16*)take(E * 128 * 2);   // reused for ts2
    u16*  tv   = (u16*)take(E * 384 * 2);   // reused for tv2
    u16*  fs1  = (u16*)take(E * 64 * 2);
    u16*  fv1  = (u16*)take(E * 192 * 2);
    float* ns_e  = (float*)take((size_t)NNODES * 64 * 4);
    float* nv_e  = (float*)take((size_t)NNODES * 192 * 4);
    float* ns2_e = (float*)take((size_t)NNODES * 64 * 4);
    float* nv2_e = (float*)take((size_t)NNODES * 192 * 4);

    // sort scratch
    int* cnt  = (int*)take(NNODES * 4);
    int* cur  = (int*)take(NNODES * 4);
    int* offs = (int*)take(NNODES * 4);
    int* perm = (int*)take(E * 4);

    // weight arena: transposed hi/lo bf16, [Npad][Kpad]
    u16* W0h  = (u16*)take(256 * 160 * 2); u16* W0l  = (u16*)take(256 * 160 * 2);
    u16* W1h  = (u16*)take(65536 * 2);     u16* W1l  = (u16*)take(65536 * 2);
    u16* W2h  = (u16*)take(65536 * 2);     u16* W2l  = (u16*)take(65536 * 2);
    u16* We0h = (u16*)take(384 * 256 * 2); u16* We0l = (u16*)take(384 * 256 * 2);
    u16* WL0h = (u16*)take(98304 * 2);     u16* WL0l = (u16*)take(98304 * 2);
    u16* WL1h = (u16*)take(65536 * 2);     u16* WL1l = (u16*)take(65536 * 2);
    u16* We1h = (u16*)take(256 * 256 * 2); u16* We1l = (u16*)take(256 * 256 * 2);
    u16* S0h  = (u16*)take(8192 * 2);      u16* S0l  = (u16*)take(8192 * 2);
    u16* V0h  = (u16*)take(8192 * 2);      u16* V0l  = (u16*)take(8192 * 2);
    u16* S1h  = (u16*)take(16384 * 2);     u16* S1l  = (u16*)take(16384 * 2);
    u16* V1h  = (u16*)take(16384 * 2);     u16* V1l  = (u16*)take(16384 * 2);
    u16* WF0h = (u16*)take(98304 * 2);     u16* WF0l = (u16*)take(98304 * 2);
    u16* WF1h = (u16*)take(32768 * 2);     u16* WF1l = (u16*)take(32768 * 2);

    // zero sort counters (ws is re-poisoned before every call)
    hipMemsetAsync(cnt, 0, NNODES * 4, stream);
    hipMemsetAsync(cur, 0, NNODES * 4, stream);

    // ---- weight prep ----
    split_w(stream, 0, tb_w0,   W0h,  W0l,  136, 256, 160, 256);
    split_w(stream, 0, tb_w1,   W1h,  W1l,  256, 256, 256, 256);
    split_w(stream, 0, tb_w2,   W2h,  W2l,  256, 256, 256, 256);
    split_w(stream, 0, env0_w,  We0h, We0l, 256, 320, 256, 384);
    split_w(stream, 0, lat1_w0, WL0h, WL0l, 384, 256, 384, 256);
    split_w(stream, 0, lat1_w1, WL1h, WL1l, 256, 256, 256, 256);
    split_w(stream, 0, env1_w,  We1h, We1l, 256, 192, 256, 256);
    split_w(stream, 0, lin0_sw, S0h,  S0l,  128, 64,  128, 64);
    split_w(stream, 0, lin0_vw, V0h,  V0l,  128, 64,  128, 64);
    split_w(stream, 1, lin1_sw, S1h,  S1l,  128, 128, 128, 128);
    split_w(stream, 1, lin1_vw, V1h,  V1l,  128, 128, 128, 128);
    split_w(stream, 0, fin_w0,  WF0h, WF0l, 384, 256, 384, 256);
    split_w(stream, 0, fin_w1,  WF1h, WF1l, 256, 128, 256, 128);

    prep_edges_k<<<(E_EDGES * 160) / 256, 256, 0, stream>>>(node_attrs, radial, lengths, eidx, X0, cut);

    // ---- counting sort by center ----
    hist_k<<<(E_EDGES + 255) / 256, 256, 0, stream>>>(eidx, cnt);
    scan_k<<<1, 256, 0, stream>>>(cnt, offs);
    scatter_k<<<(E_EDGES + 255) / 256, 256, 0, stream>>>(eidx, offs, cur, perm);

    // ---- stage A: two-body MLP -> latents ----
    mgemm2(stream, 1, X0, 160, 160, nullptr, 0, 0, W0h, W0l, 160, hA, 256, E_EDGES, 256, nullptr, nullptr, nullptr, nullptr);
    mgemm2(stream, 1, hA, 256, 256, nullptr, 0, 0, W1h, W1l, 256, hB, 256, E_EDGES, 256, nullptr, nullptr, nullptr, nullptr);
    mgemm2(stream, 2, hB, 256, 256, nullptr, 0, 0, W2h, W2l, 256, lat, 256, E_EDGES, 256, cut, nullptr, nullptr, nullptr);

    // ---- stage B ----
    mgemm2(stream, 0, lat, 256, 256, nullptr, 0, 0, We0h, We0l, 256, wall, 320, E_EDGES, 320, nullptr, nullptr, nullptr, nullptr);
    envsum_k<320><<<NNODES, 64, 0, stream>>>(wall, ang, perm, offs, cnt, envlin0, ns_e, nv_e);
    tp0f_k<<<(E_EDGES * 64) / 256, 256, 0, stream>>>(wall, ang, ns_e, nv_e, eidx, ts, tv);
    {   // lin0 (N=64): 2-wave kernel
        dim3 block(128);
        dim3 g1((E_EDGES + 127) / 128, 1);
        mgemm_k<<<g1, block, 0, stream>>>(ts, 128, 128, S0h, S0l, 128, fs1, 64, E_EDGES);
        dim3 g2((3 * E_EDGES + 127) / 128, 1);
        mgemm_k<<<g2, block, 0, stream>>>(tv, 128, 128, V0h, V0l, 128, fv1, 64, 3 * E_EDGES);
    }

    // ---- latent update MLP + fused residual blend ----
    mgemm2(stream, 1, lat, 256, 256, ts, 128, 128, WL0h, WL0l, 384, hA, 256, E_EDGES, 256, nullptr, nullptr, nullptr, nullptr);
    mgemm2(stream, 3, hA, 256, 256, nullptr, 0, 0, WL1h, WL1l, 256, lat, 256, E_EDGES, 256, cut, res_p, nullptr, nullptr);

    // ---- stage C ----
    mgemm2(stream, 0, lat, 256, 256, nullptr, 0, 0, We1h, We1l, 256, wall, 192, E_EDGES, 192, nullptr, nullptr, nullptr, nullptr);
    envsum_k<192><<<NNODES, 64, 0, stream>>>(wall, ang, perm, offs, cnt, envlin1, ns2_e, nv2_e);
    tp1f_k<<<(E_EDGES * 64) / 256, 256, 0, stream>>>(fs1, fv1, wall, ns2_e, nv2_e, eidx, ts, tv);

    // ---- final MLP (fin) BEFORE the lin1 GEMMs so their epilogues can fuse
    //      the output assembly (out_k eliminated) ----
    mgemm2(stream, 1, lat, 256, 256, ts, 128, 128, WF0h, WF0l, 384, hA, 256, E_EDGES, 256, nullptr, nullptr, nullptr, nullptr);
    mgemm2(stream, 0, hA, 256, 256, nullptr, 0, 0, WF1h, WF1l, 256, hB, 128, E_EDGES, 128, nullptr, nullptr, nullptr, nullptr);

    // ---- lin1 GEMMs fused with output assembly ----
    // scalar half: out[e*512 + o*64+v] = acc * fin  (f32, full precision acc)
    mgemm2(stream, 4, ts, 128, 128, nullptr, 0, 0, S1h, S1l, 128, nullptr, 0, E_EDGES, 128, nullptr, nullptr, hB, (float*)d_out);
    // vector half: row=e*3+c, col=o*64+v -> out[e*512 + 128 + o*192 + v*3 + c]
    mgemm2(stream, 5, tv, 128, 128, nullptr, 0, 0, V1h, V1l, 128, nullptr, 0, 3 * E_EDGES, 128, nullptr, nullptr, nullptr, (float*)d_out);
}

// Round 6
// 1127.204 us; speedup vs baseline: 1.0882x; 1.0882x over previous
//
#include <hip/hip_runtime.h>
#include <math.h>

typedef unsigned short u16;
typedef unsigned int   u32;

#define E_EDGES 100000
#define NNODES  5000
#define INV_SQRT3 0.57735026918962576f
#define INV_AVG   0.05f

typedef short bf16x8 __attribute__((ext_vector_type(8)));
typedef float f32x4  __attribute__((ext_vector_type(4)));
typedef int   i32x4  __attribute__((ext_vector_type(4)));

__device__ __forceinline__ float us2f(u16 u) {
    union { float f; u32 i; } c; c.i = ((u32)u) << 16; return c.f;
}
__device__ __forceinline__ u16 f2us(float f) {
    union { float f; u32 i; } c; c.f = f;
    u32 x = c.i;
    x += 0x7fffu + ((x >> 16) & 1u);   // round-to-nearest-even bf16
    return (u16)(x >> 16);
}
__device__ __forceinline__ float siluf(float x) { return x / (1.f + expf(-x)); }

// ---------------------------------------------------------------------------
// MFMA GEMM, 4 waves, tile 128x128: Y = epi( concat(X1,X2) @ (W_hi+W_lo) )
// W stored transposed [n][k], n padded to >= grid cols, k padded to mult 32.
// Wave w: rows (w>>1)*64.., cols (w&1)*64..  (4x4 frags of 16x16).
// LDS granule-major with XOR swizzle (R6): byte off = g*2048 + ((row^(g<<1))*16).
//   write side: for fixed row, g=0..3 hit 4 distinct bank-groups -> <=2-way
//   (was 4-way: bank 4*(row%8) indep. of g, 7.2M conflict cycles/dispatch).
//   read side: 16 consecutive rows XOR const -> permuted residues, still
//   2-way alias (free, m136). ds_read/MFMA math unchanged.
// STAGING: reg-staged, coalesced (4 lanes = one row's 64B k-slice), depth-1
// (R5's depth-2 regressed: nx1=nx2 reg-copy forces full vmcnt drain per iter).
// EPI: 0 none, 1 silu, 2 cut-scale, 3 residual blend (reads old Y, cut, resp)
//      4 scalar-out fusion: OUTF[row*512+col] = acc * bf16(F[row*128+col])
//      5 vector-out fusion: row=e*3+c, col=o*64+v ->
//                           OUTF[e*512 + 128 + o*192 + v*3 + c] = acc
// ---------------------------------------------------------------------------
template <int EPI>
__global__ __launch_bounds__(256) void mgemm2_k(
    const u16* __restrict__ X1, int ldx1, int K1,
    const u16* __restrict__ X2, int ldx2, int K2,
    const u16* __restrict__ Wh, const u16* __restrict__ Wl, int ldk,
    u16* __restrict__ Y, int ldy, int M, int N,
    const float* __restrict__ cut, const float* __restrict__ resp,
    const u16* __restrict__ F, float* __restrict__ OUTF)
{
    __shared__ short lA[2][4096];    // 16KB : g*2048B + swz(row)*16B
    __shared__ short lBh[2][4096];   // 16KB
    __shared__ short lBl[2][4096];   // 16KB
    const int lane = threadIdx.x & 63;
    const int w    = threadIdx.x >> 6;    // wave 0..3
    const int q    = lane >> 4;           // k-granule (read side)
    const int r16  = lane & 15;
    const int sr   = lane >> 2;           // staging: row-in-group 0..15
    const int sg   = lane & 3;            // staging: k-granule 0..3
    const int m0 = blockIdx.x * 128;
    const int n0 = blockIdx.y * 128;
    const int wr0 = (w >> 1) * 64;        // wave row base in tile
    const int wc0 = (w & 1) * 64;         // wave col base in tile
    const int Kt = K1 + K2;
    const int j0 = w * 2, j1 = w * 2 + 1; // this wave's 16-row chunks

    struct Stage { i32x4 a0, a1, b0h, b1h, b0l, b1l; };
    auto load_tile = [&](int k0) -> Stage {
        const u16* xs; int ldx, kb;
        if (k0 < K1) { xs = X1; ldx = ldx1; kb = k0; }
        else         { xs = X2; ldx = ldx2; kb = k0 - K1; }
        Stage s;
        int row0 = m0 + j0 * 16 + sr; row0 = row0 < M ? row0 : M - 1;
        int row1 = m0 + j1 * 16 + sr; row1 = row1 < M ? row1 : M - 1;
        s.a0 = *(const i32x4*)(xs + (size_t)row0 * ldx + kb + sg * 8);
        s.a1 = *(const i32x4*)(xs + (size_t)row1 * ldx + kb + sg * 8);
        const size_t wo0 = (size_t)(n0 + j0 * 16 + sr) * ldk + k0 + sg * 8;
        const size_t wo1 = (size_t)(n0 + j1 * 16 + sr) * ldk + k0 + sg * 8;
        s.b0h = *(const i32x4*)(Wh + wo0);
        s.b1h = *(const i32x4*)(Wh + wo1);
        s.b0l = *(const i32x4*)(Wl + wo0);
        s.b1l = *(const i32x4*)(Wl + wo1);
        return s;
    };
    auto write_tile = [&](const Stage& s, int buf) {
        char* A  = (char*)&lA[buf][0];
        char* Bh = (char*)&lBh[buf][0];
        char* Bl = (char*)&lBl[buf][0];
        const int o0 = sg * 2048 + (((j0 * 16 + sr) ^ (sg << 1)) << 4);
        const int o1 = sg * 2048 + (((j1 * 16 + sr) ^ (sg << 1)) << 4);
        *(i32x4*)(A  + o0) = s.a0;  *(i32x4*)(A  + o1) = s.a1;
        *(i32x4*)(Bh + o0) = s.b0h; *(i32x4*)(Bh + o1) = s.b1h;
        *(i32x4*)(Bl + o0) = s.b0l; *(i32x4*)(Bl + o1) = s.b1l;
    };

    f32x4 acc[4][4];
#pragma unroll
    for (int i = 0; i < 4; ++i)
#pragma unroll
        for (int j = 0; j < 4; ++j) acc[i][j] = (f32x4){0.f, 0.f, 0.f, 0.f};

    {
        Stage s0 = load_tile(0);
        write_tile(s0, 0);
    }
    __syncthreads();
    int cur = 0;
    const int qx = q << 1;                 // read-side swizzle constant
    for (int k0 = 0; k0 < Kt; k0 += 32) {
        const bool more = (k0 + 32 < Kt);
        Stage nx;
        if (more) nx = load_tile(k0 + 32);   // issue loads early: hide under MFMA
        bf16x8 a[4], bh[4], bl[4];
#pragma unroll
        for (int rt = 0; rt < 4; ++rt)
            a[rt] = *(const bf16x8*)&lA[cur][q * 1024 + (((wr0 + rt * 16 + r16) ^ qx) * 8)];
#pragma unroll
        for (int ct = 0; ct < 4; ++ct) {
            bh[ct] = *(const bf16x8*)&lBh[cur][q * 1024 + (((wc0 + ct * 16 + r16) ^ qx) * 8)];
            bl[ct] = *(const bf16x8*)&lBl[cur][q * 1024 + (((wc0 + ct * 16 + r16) ^ qx) * 8)];
        }
#pragma unroll
        for (int rt = 0; rt < 4; ++rt)
#pragma unroll
            for (int ct = 0; ct < 4; ++ct) {
                acc[rt][ct] = __builtin_amdgcn_mfma_f32_16x16x32_bf16(a[rt], bh[ct], acc[rt][ct], 0, 0, 0);
                acc[rt][ct] = __builtin_amdgcn_mfma_f32_16x16x32_bf16(a[rt], bl[ct], acc[rt][ct], 0, 0, 0);
            }
        if (more) write_tile(nx, cur ^ 1);   // vmcnt waits land here, post-MFMA
        __syncthreads();
        cur ^= 1;
    }
    // ---- epilogue ----
    float c1 = 0.f, c2a = 0.f;
    if (EPI == 3) {
        float aa = 1.f / (1.f + expf(-resp[1]));
        c1 = sqrtf(1.f - aa);
        c2a = sqrtf(aa);
    }
#pragma unroll
    for (int rt = 0; rt < 4; ++rt) {
#pragma unroll
        for (int r = 0; r < 4; ++r) {
            const int row = m0 + wr0 + rt * 16 + q * 4 + r;
            if (row < M) {
                float sc = 1.f;
                if (EPI == 2) sc = cut[row];
                float c2 = 0.f;
                if (EPI == 3) c2 = c2a * cut[row];
                int e3 = 0, cc = 0;
                if (EPI == 5) { e3 = row / 3; cc = row - e3 * 3; }
#pragma unroll
                for (int ct = 0; ct < 4; ++ct) {
                    const int col = n0 + wc0 + ct * 16 + r16;
                    if (col < N) {
                        float v = acc[rt][ct][r];
                        if (EPI == 1) v = siluf(v);
                        if (EPI == 2) v *= sc;
                        if (EPI == 3) v = c1 * us2f(Y[(size_t)row * ldy + col]) + c2 * v;
                        if (EPI == 4) {
                            OUTF[(size_t)row * 512 + col] = v * us2f(F[(size_t)row * 128 + col]);
                        } else if (EPI == 5) {
                            OUTF[(size_t)e3 * 512 + 128 + (col >> 6) * 192 + (col & 63) * 3 + cc] = v;
                        } else {
                            Y[(size_t)row * ldy + col] = f2us(v);
                        }
                    }
                }
            }
        }
    }
}

// ---------------------------------------------------------------------------
// 2-wave 128x64 variant (N=64 lin0 GEMMs) — same swizzled depth-1 scheme.
// B buffer granule = 1024B (64 cols x 16B), same XOR swizzle on col.
// ---------------------------------------------------------------------------
__global__ __launch_bounds__(128) void mgemm_k(
    const u16* __restrict__ X1, int ldx1, int K1,
    const u16* __restrict__ Wh, const u16* __restrict__ Wl, int ldk,
    u16* __restrict__ Y, int ldy, int M)
{
    __shared__ short lA[2][4096];
    __shared__ short lBh[2][2048];
    __shared__ short lBl[2][2048];
    const int lane = threadIdx.x & 63;
    const int w    = threadIdx.x >> 6;
    const int q    = lane >> 4;
    const int r16  = lane & 15;
    const int sr   = lane >> 2;
    const int sg   = lane & 3;
    const int m0 = blockIdx.x * 128;
    const int n0 = blockIdx.y * 64;
    const int Kt = K1;

    struct Stage { i32x4 a[4]; i32x4 bh[2]; i32x4 bl[2]; };
    auto load_tile = [&](int k0) -> Stage {
        Stage s;
#pragma unroll
        for (int i = 0; i < 4; ++i) {
            const int j = w * 4 + i;
            int row = m0 + j * 16 + sr; row = row < M ? row : M - 1;
            s.a[i] = *(const i32x4*)(X1 + (size_t)row * ldx1 + k0 + sg * 8);
        }
#pragma unroll
        for (int i = 0; i < 2; ++i) {
            const int j = w * 2 + i;
            const size_t wo = (size_t)(n0 + j * 16 + sr) * ldk + k0 + sg * 8;
            s.bh[i] = *(const i32x4*)(Wh + wo);
            s.bl[i] = *(const i32x4*)(Wl + wo);
        }
        return s;
    };
    auto write_tile = [&](const Stage& s, int buf) {
        char* A  = (char*)&lA[buf][0];
        char* Bh = (char*)&lBh[buf][0];
        char* Bl = (char*)&lBl[buf][0];
#pragma unroll
        for (int i = 0; i < 4; ++i) {
            const int j = w * 4 + i;
            *(i32x4*)(A + sg * 2048 + (((j * 16 + sr) ^ (sg << 1)) << 4)) = s.a[i];
        }
#pragma unroll
        for (int i = 0; i < 2; ++i) {
            const int j = w * 2 + i;
            const int o = sg * 1024 + (((j * 16 + sr) ^ (sg << 1)) << 4);
            *(i32x4*)(Bh + o) = s.bh[i];
            *(i32x4*)(Bl + o) = s.bl[i];
        }
    };

    f32x4 acc[4][4];
#pragma unroll
    for (int i = 0; i < 4; ++i)
#pragma unroll
        for (int j = 0; j < 4; ++j) acc[i][j] = (f32x4){0.f, 0.f, 0.f, 0.f};

    {
        Stage s0 = load_tile(0);
        write_tile(s0, 0);
    }
    __syncthreads();
    int cur = 0;
    const int qx = q << 1;
    for (int k0 = 0; k0 < Kt; k0 += 32) {
        const bool more = (k0 + 32 < Kt);
        Stage nx;
        if (more) nx = load_tile(k0 + 32);
        bf16x8 a[4], bh[4], bl[4];
#pragma unroll
        for (int rt = 0; rt < 4; ++rt)
            a[rt] = *(const bf16x8*)&lA[cur][q * 1024 + (((w * 64 + rt * 16 + r16) ^ qx) * 8)];
#pragma unroll
        for (int ct = 0; ct < 4; ++ct) {
            bh[ct] = *(const bf16x8*)&lBh[cur][q * 512 + (((ct * 16 + r16) ^ qx) * 8)];
            bl[ct] = *(const bf16x8*)&lBl[cur][q * 512 + (((ct * 16 + r16) ^ qx) * 8)];
        }
#pragma unroll
        for (int rt = 0; rt < 4; ++rt)
#pragma unroll
            for (int ct = 0; ct < 4; ++ct) {
                acc[rt][ct] = __builtin_amdgcn_mfma_f32_16x16x32_bf16(a[rt], bh[ct], acc[rt][ct], 0, 0, 0);
                acc[rt][ct] = __builtin_amdgcn_mfma_f32_16x16x32_bf16(a[rt], bl[ct], acc[rt][ct], 0, 0, 0);
            }
        if (more) write_tile(nx, cur ^ 1);
        __syncthreads();
        cur ^= 1;
    }
#pragma unroll
    for (int rt = 0; rt < 4; ++rt) {
#pragma unroll
        for (int r = 0; r < 4; ++r) {
            const int row = m0 + w * 64 + rt * 16 + q * 4 + r;
            if (row < M) {
#pragma unroll
                for (int ct = 0; ct < 4; ++ct)
                    Y[(size_t)row * ldy + n0 + ct * 16 + r16] = f2us(acc[rt][ct][r]);
            }
        }
    }
}

// ---------------------------------------------------------------------------
// Weight prep: f32 W (Ksrc x Nsrc row-major) -> bf16 hi/lo transposed [n][k],
// padded to Npad x Kpad with zeros.
// MODE 0: standard. MODE 1: lin1 (2,2,64,64) [i][o][u][v], k=i*64+u, n=o*64+v.
// ---------------------------------------------------------------------------
template <int MODE>
__global__ __launch_bounds__(256) void split_w_k(
    const float* __restrict__ src, u16* __restrict__ hi, u16* __restrict__ lo,
    int Ksrc, int Nsrc, int Kpad, int Npad)
{
    int idx = blockIdx.x * 256 + threadIdx.x;
    if (idx >= Npad * Kpad) return;
    int n = idx / Kpad, k = idx - n * Kpad;
    float wv = 0.f;
    if (k < Ksrc && n < Nsrc) {
        if (MODE == 0) wv = src[(size_t)k * Nsrc + n];
        else           wv = src[(k >> 6) * 8192 + (n >> 6) * 4096 + (k & 63) * 64 + (n & 63)];
    }
    u16 h = f2us(wv);
    hi[idx] = h;
    lo[idx] = f2us(wv - us2f(h));
}

// ---------------------------------------------------------------------------
// prep: X0 = [node[center] | node[neigh] | radial | 0pad] (E x 160 bf16), cut
// ---------------------------------------------------------------------------
__global__ __launch_bounds__(256) void prep_edges_k(
    const float* __restrict__ na, const float* __restrict__ radial,
    const float* __restrict__ lengths, const int* __restrict__ eidx,
    u16* __restrict__ X0, float* __restrict__ cut)
{
    int idx = blockIdx.x * 256 + threadIdx.x;
    if (idx >= E_EDGES * 160) return;
    int e = idx / 160;
    int k = idx - e * 160;
    float v = 0.f;
    if (k < 64)       v = na[(size_t)eidx[e] * 64 + k];
    else if (k < 128) v = na[(size_t)eidx[E_EDGES + e] * 64 + (k - 64)];
    else if (k < 136) v = radial[(size_t)e * 8 + (k - 128)];
    X0[idx] = f2us(v);
    if (k == 136) {
        float x = lengths[e] * 0.2f;           // r / R_MAX
        float x3 = x * x * x;
        float x6 = x3 * x3, x7 = x6 * x, x8 = x7 * x;
        float o = 1.f - 28.f * x6 + 48.f * x7 - 21.f * x8;
        cut[e] = (x < 1.f) ? o : 0.f;
    }
}

// ---------------------------------------------------------------------------
// counting sort of edges by center node
// ---------------------------------------------------------------------------
__global__ __launch_bounds__(256) void hist_k(const int* __restrict__ eidx, int* __restrict__ cnt)
{
    int e = blockIdx.x * 256 + threadIdx.x;
    if (e < E_EDGES) atomicAdd(&cnt[eidx[e]], 1);
}

__global__ __launch_bounds__(256) void scan_k(const int* __restrict__ cnt, int* __restrict__ offs)
{
    __shared__ int buf[256];
    __shared__ int base;
    if (threadIdx.x == 0) base = 0;
    __syncthreads();
    for (int start = 0; start < NNODES; start += 256) {
        int i = start + threadIdx.x;
        int v = (i < NNODES) ? cnt[i] : 0;
        buf[threadIdx.x] = v;
        __syncthreads();
        for (int d = 1; d < 256; d <<= 1) {
            int t = (threadIdx.x >= d) ? buf[threadIdx.x - d] : 0;
            __syncthreads();
            buf[threadIdx.x] += t;
            __syncthreads();
        }
        if (i < NNODES) offs[i] = base + buf[threadIdx.x] - v;
        __syncthreads();
        if (threadIdx.x == 255) base += buf[255];
        __syncthreads();
    }
}

__global__ __launch_bounds__(256) void scatter_k(
    const int* __restrict__ eidx, const int* __restrict__ offs,
    int* __restrict__ cur, int* __restrict__ perm)
{
    int e = blockIdx.x * 256 + threadIdx.x;
    if (e >= E_EDGES) return;
    int n = eidx[e];
    int p = atomicAdd(&cur[n], 1);
    perm[offs[n] + p] = e;
}

// ---------------------------------------------------------------------------
// per-node env segment-sum + envlin (replaces atomics + nodelin)
// LD = wall row stride (320 stage B, 192 stage C); env weights at cols [0,128)
// ---------------------------------------------------------------------------
template <int LD>
__global__ __launch_bounds__(64) void envsum_k(
    const u16* __restrict__ wall, const float* __restrict__ ang,
    const int* __restrict__ perm, const int* __restrict__ offs, const int* __restrict__ cnt,
    const float* __restrict__ envlin,
    float* __restrict__ ns_e, float* __restrict__ nv_e)
{
    const int n = blockIdx.x, lane = threadIdx.x;
    const int s = offs[n], c = cnt[n];
    float a0 = 0.f, a1 = 0.f, a2 = 0.f, a3 = 0.f;
    for (int i = 0; i < c; ++i) {
        int e = perm[s + i];
        u32 pw = *(const u32*)(wall + (size_t)e * LD + 2 * lane);
        float we0 = us2f((u16)(pw & 0xffffu)), we1 = us2f((u16)(pw >> 16));
        float4 sh = *(const float4*)(ang + (size_t)e * 4);
        a0 = fmaf(we0, sh.x, a0);
        a1 = fmaf(we1, sh.y, a1);
        a2 = fmaf(we1, sh.z, a2);
        a3 = fmaf(we1, sh.w, a3);
    }
    __shared__ float ss[64], sv0[64], sv1[64], sv2[64];
    ss[lane] = a0; sv0[lane] = a1; sv1[lane] = a2; sv2[lane] = a3;
    __syncthreads();
    const float* L0 = envlin;
    const float* L1 = envlin + 4096;
    float b0 = 0.f, b1 = 0.f, b2 = 0.f, b3 = 0.f;
#pragma unroll 8
    for (int u = 0; u < 64; ++u) {
        float l0 = L0[u * 64 + lane], l1 = L1[u * 64 + lane];
        b0 = fmaf(ss[u],  l0, b0);
        b1 = fmaf(sv0[u], l1, b1);
        b2 = fmaf(sv1[u], l1, b2);
        b3 = fmaf(sv2[u], l1, b3);
    }
    ns_e[n * 64 + lane]           = b0 * INV_AVG;
    nv_e[n * 192 + lane]          = b1 * INV_AVG;
    nv_e[n * 192 + 64 + lane]     = b2 * INV_AVG;
    nv_e[n * 192 + 128 + lane]    = b3 * INV_AVG;
}

// ---------------------------------------------------------------------------
// stage-B fused gate + tensor product (reads wall directly, no fsg/fvg)
// ---------------------------------------------------------------------------
__global__ __launch_bounds__(256) void tp0f_k(
    const u16* __restrict__ wall, const float* __restrict__ ang,
    const float* __restrict__ ns_e, const float* __restrict__ nv_e,
    const int* __restrict__ eidx, u16* __restrict__ ts, u16* __restrict__ tv)
{
    int idx = blockIdx.x * 256 + threadIdx.x;
    if (idx >= E_EDGES * 64) return;
    int e = idx >> 6, u = idx & 63;
    int ce = eidx[e];
    const u16* wr = wall + (size_t)e * 320;
    float g   = us2f(wr[128 + u]);
    u32 pw = *(const u32*)&wr[192 + 2 * u];
    float wf0 = us2f((u16)(pw & 0xffffu)), wf1 = us2f((u16)(pw >> 16));
    float4 sh = *(const float4*)(ang + (size_t)e * 4);
    float f  = wf0 * sh.x * g;
    float b0 = wf1 * sh.y * g;
    float b1 = wf1 * sh.z * g;
    float b2 = wf1 * sh.w * g;
    float ns = ns_e[ce * 64 + u];
    float n0 = nv_e[ce * 192 + u], n1 = nv_e[ce * 192 + 64 + u], n2 = nv_e[ce * 192 + 128 + u];
    ts[(size_t)e * 128 + u]      = f2us(f * ns);
    ts[(size_t)e * 128 + 64 + u] = f2us((b0 * n0 + b1 * n1 + b2 * n2) * INV_SQRT3);
    size_t tb = (size_t)e * 384;
    tv[tb + u]             = f2us(f * n0 * INV_SQRT3);
    tv[tb + 128 + u]       = f2us(f * n1 * INV_SQRT3);
    tv[tb + 256 + u]       = f2us(f * n2 * INV_SQRT3);
    tv[tb + 64 + u]        = f2us(b0 * ns * INV_SQRT3);
    tv[tb + 128 + 64 + u]  = f2us(b1 * ns * INV_SQRT3);
    tv[tb + 256 + 64 + u]  = f2us(b2 * ns * INV_SQRT3);
}

// ---------------------------------------------------------------------------
// stage-C fused gate + tensor product (gates lin0 outputs fs1/fv1 on the fly)
// ---------------------------------------------------------------------------
__global__ __launch_bounds__(256) void tp1f_k(
    const u16* __restrict__ fs1, const u16* __restrict__ fv1,
    const u16* __restrict__ wall,
    const float* __restrict__ ns_e, const float* __restrict__ nv_e,
    const int* __restrict__ eidx, u16* __restrict__ ts, u16* __restrict__ tv)
{
    int idx = blockIdx.x * 256 + threadIdx.x;
    if (idx >= E_EDGES * 64) return;
    int e = idx >> 6, u = idx & 63;
    int ce = eidx[e];
    float g = us2f(wall[(size_t)e * 192 + 128 + u]);
    float f  = us2f(fs1[(size_t)e * 64 + u]) * g;
    float b0 = us2f(fv1[((size_t)e * 3 + 0) * 64 + u]) * g;
    float b1 = us2f(fv1[((size_t)e * 3 + 1) * 64 + u]) * g;
    float b2 = us2f(fv1[((size_t)e * 3 + 2) * 64 + u]) * g;
    float ns = ns_e[ce * 64 + u];
    float n0 = nv_e[ce * 192 + u], n1 = nv_e[ce * 192 + 64 + u], n2 = nv_e[ce * 192 + 128 + u];
    ts[(size_t)e * 128 + u]      = f2us(f * ns);
    ts[(size_t)e * 128 + 64 + u] = f2us((b0 * n0 + b1 * n1 + b2 * n2) * INV_SQRT3);
    size_t tb = (size_t)e * 384;
    tv[tb + u]             = f2us(f * n0 * INV_SQRT3);
    tv[tb + 128 + u]       = f2us(f * n1 * INV_SQRT3);
    tv[tb + 256 + u]       = f2us(f * n2 * INV_SQRT3);
    tv[tb + 64 + u]        = f2us(b0 * ns * INV_SQRT3);
    tv[tb + 128 + 64 + u]  = f2us(b1 * ns * INV_SQRT3);
    tv[tb + 256 + 64 + u]  = f2us(b2 * ns * INV_SQRT3);
}

// ---------------------------------------------------------------------------
static void mgemm2(hipStream_t s, int epi,
                   const u16* X1, int ldx1, int K1,
                   const u16* X2, int ldx2, int K2,
                   const u16* Wh, const u16* Wl, int ldk,
                   u16* Y, int ldy, int M, int N,
                   const float* cut, const float* resp,
                   const u16* F, float* OUTF)
{
    dim3 grid((M + 127) / 128, (N + 127) / 128);
    dim3 block(256);
    if (epi == 0)      mgemm2_k<0><<<grid, block, 0, s>>>(X1, ldx1, K1, X2, ldx2, K2, Wh, Wl, ldk, Y, ldy, M, N, cut, resp, F, OUTF);
    else if (epi == 1) mgemm2_k<1><<<grid, block, 0, s>>>(X1, ldx1, K1, X2, ldx2, K2, Wh, Wl, ldk, Y, ldy, M, N, cut, resp, F, OUTF);
    else if (epi == 2) mgemm2_k<2><<<grid, block, 0, s>>>(X1, ldx1, K1, X2, ldx2, K2, Wh, Wl, ldk, Y, ldy, M, N, cut, resp, F, OUTF);
    else if (epi == 3) mgemm2_k<3><<<grid, block, 0, s>>>(X1, ldx1, K1, X2, ldx2, K2, Wh, Wl, ldk, Y, ldy, M, N, cut, resp, F, OUTF);
    else if (epi == 4) mgemm2_k<4><<<grid, block, 0, s>>>(X1, ldx1, K1, X2, ldx2, K2, Wh, Wl, ldk, Y, ldy, M, N, cut, resp, F, OUTF);
    else               mgemm2_k<5><<<grid, block, 0, s>>>(X1, ldx1, K1, X2, ldx2, K2, Wh, Wl, ldk, Y, ldy, M, N, cut, resp, F, OUTF);
}

static void split_w(hipStream_t s, int mode, const float* src, u16* hi, u16* lo,
                    int Ksrc, int Nsrc, int Kpad, int Npad)
{
    int n = Npad * Kpad;
    dim3 grid((n + 255) / 256), block(256);
    if (mode == 0) split_w_k<0><<<grid, block, 0, s>>>(src, hi, lo, Ksrc, Nsrc, Kpad, Npad);
    else           split_w_k<1><<<grid, block, 0, s>>>(src, hi, lo, Ksrc, Nsrc, Kpad, Npad);
}

extern "C" void kernel_launch(void* const* d_in, const int* in_sizes, int n_in,
                              void* d_out, int out_size, void* d_ws, size_t ws_size,
                              hipStream_t stream)
{
    const float* node_attrs = (const float*)d_in[0];
    const float* radial     = (const float*)d_in[1];
    const float* ang        = (const float*)d_in[2];
    const float* lengths    = (const float*)d_in[3];
    const int*   eidx       = (const int*)d_in[4];
    const float* tb_w0      = (const float*)d_in[5];
    const float* tb_w1      = (const float*)d_in[6];
    const float* tb_w2      = (const float*)d_in[7];
    const float* lat1_w0    = (const float*)d_in[8];
    const float* lat1_w1    = (const float*)d_in[9];
    const float* env0_w     = (const float*)d_in[10];
    const float* env1_w     = (const float*)d_in[11];
    const float* envlin0    = (const float*)d_in[12];
    const float* envlin1    = (const float*)d_in[13];
    const float* lin0_sw    = (const float*)d_in[14];
    const float* lin0_vw    = (const float*)d_in[15];
    const float* lin1_sw    = (const float*)d_in[16];
    const float* lin1_vw    = (const float*)d_in[17];
    const float* fin_w0     = (const float*)d_in[18];
    const float* fin_w1     = (const float*)d_in[19];
    const float* res_p      = (const float*)d_in[20];

    const size_t E = E_EDGES;
    unsigned char* ws = (unsigned char*)d_ws;
    size_t off = 0;
    auto take = [&](size_t n) -> void* {
        void* p = ws + off;
        off += (n + 255) & ~(size_t)255;
        return p;
    };
    u16*  X0   = (u16*)take(E * 160 * 2);
    float* cut = (float*)take(E * 4);
    u16*  hA   = (u16*)take(E * 256 * 2);
    u16*  hB   = (u16*)take(E * 256 * 2);
    u16*  lat  = (u16*)take(E * 256 * 2);
    u16*  wall = (u16*)take(E * 320 * 2);   // reused for w_all1 (E x 192)
    u16*  ts   = (u16*)take(E * 128 * 2);   // reused for ts2
    u16*  tv   = (u16*)take(E * 384 * 2);   // reused for tv2
    u16*  fs1  = (u16*)take(E * 64 * 2);
    u16*  fv1  = (u16*)take(E * 192 * 2);
    float* ns_e  = (float*)take((size_t)NNODES * 64 * 4);
    float* nv_e  = (float*)take((size_t)NNODES * 192 * 4);
    float* ns2_e = (float*)take((size_t)NNODES * 64 * 4);
    float* nv2_e = (float*)take((size_t)NNODES * 192 * 4);

    // sort scratch
    int* cnt  = (int*)take(NNODES * 4);
    int* cur  = (int*)take(NNODES * 4);
    int* offs = (int*)take(NNODES * 4);
    int* perm = (int*)take(E * 4);

    // weight arena: transposed hi/lo bf16, [Npad][Kpad]
    u16* W0h  = (u16*)take(256 * 160 * 2); u16* W0l  = (u16*)take(256 * 160 * 2);
    u16* W1h  = (u16*)take(65536 * 2);     u16* W1l  = (u16*)take(65536 * 2);
    u16* W2h  = (u16*)take(65536 * 2);     u16* W2l  = (u16*)take(65536 * 2);
    u16* We0h = (u16*)take(384 * 256 * 2); u16* We0l = (u16*)take(384 * 256 * 2);
    u16* WL0h = (u16*)take(98304 * 2);     u16* WL0l = (u16*)take(98304 * 2);
    u16* WL1h = (u16*)take(65536 * 2);     u16* WL1l = (u16*)take(65536 * 2);
    u16* We1h = (u16*)take(256 * 256 * 2); u16* We1l = (u16*)take(256 * 256 * 2);
    u16* S0h  = (u16*)take(8192 * 2);      u16* S0l  = (u16*)take(8192 * 2);
    u16* V0h  = (u16*)take(8192 * 2);      u16* V0l  = (u16*)take(8192 * 2);
    u16* S1h  = (u16*)take(16384 * 2);     u16* S1l  = (u16*)take(16384 * 2);
    u16* V1h  = (u16*)take(16384 * 2);     u16* V1l  = (u16*)take(16384 * 2);
    u16* WF0h = (u16*)take(98304 * 2);     u16* WF0l = (u16*)take(98304 * 2);
    u16* WF1h = (u16*)take(32768 * 2);     u16* WF1l = (u16*)take(32768 * 2);

    // zero sort counters (ws is re-poisoned before every call)
    hipMemsetAsync(cnt, 0, NNODES * 4, stream);
    hipMemsetAsync(cur, 0, NNODES * 4, stream);

    // ---- weight prep ----
    split_w(stream, 0, tb_w0,   W0h,  W0l,  136, 256, 160, 256);
    split_w(stream, 0, tb_w1,   W1h,  W1l,  256, 256, 256, 256);
    split_w(stream, 0, tb_w2,   W2h,  W2l,  256, 256, 256, 256);
    split_w(stream, 0, env0_w,  We0h, We0l, 256, 320, 256, 384);
    split_w(stream, 0, lat1_w0, WL0h, WL0l, 384, 256, 384, 256);
    split_w(stream, 0, lat1_w1, WL1h, WL1l, 256, 256, 256, 256);
    split_w(stream, 0, env1_w,  We1h, We1l, 256, 192, 256, 256);
    split_w(stream, 0, lin0_sw, S0h,  S0l,  128, 64,  128, 64);
    split_w(stream, 0, lin0_vw, V0h,  V0l,  128, 64,  128, 64);
    split_w(stream, 1, lin1_sw, S1h,  S1l,  128, 128, 128, 128);
    split_w(stream, 1, lin1_vw, V1h,  V1l,  128, 128, 128, 128);
    split_w(stream, 0, fin_w0,  WF0h, WF0l, 384, 256, 384, 256);
    split_w(stream, 0, fin_w1,  WF1h, WF1l, 256, 128, 256, 128);

    prep_edges_k<<<(E_EDGES * 160) / 256, 256, 0, stream>>>(node_attrs, radial, lengths, eidx, X0, cut);

    // ---- counting sort by center ----
    hist_k<<<(E_EDGES + 255) / 256, 256, 0, stream>>>(eidx, cnt);
    scan_k<<<1, 256, 0, stream>>>(cnt, offs);
    scatter_k<<<(E_EDGES + 255) / 256, 256, 0, stream>>>(eidx, offs, cur, perm);

    // ---- stage A: two-body MLP -> latents ----
    mgemm2(stream, 1, X0, 160, 160, nullptr, 0, 0, W0h, W0l, 160, hA, 256, E_EDGES, 256, nullptr, nullptr, nullptr, nullptr);
    mgemm2(stream, 1, hA, 256, 256, nullptr, 0, 0, W1h, W1l, 256, hB, 256, E_EDGES, 256, nullptr, nullptr, nullptr, nullptr);
    mgemm2(stream, 2, hB, 256, 256, nullptr, 0, 0, W2h, W2l, 256, lat, 256, E_EDGES, 256, cut, nullptr, nullptr, nullptr);

    // ---- stage B ----
    mgemm2(stream, 0, lat, 256, 256, nullptr, 0, 0, We0h, We0l, 256, wall, 320, E_EDGES, 320, nullptr, nullptr, nullptr, nullptr);
    envsum_k<320><<<NNODES, 64, 0, stream>>>(wall, ang, perm, offs, cnt, envlin0, ns_e, nv_e);
    tp0f_k<<<(E_EDGES * 64) / 256, 256, 0, stream>>>(wall, ang, ns_e, nv_e, eidx, ts, tv);
    {   // lin0 (N=64): 2-wave kernel
        dim3 block(128);
        dim3 g1((E_EDGES + 127) / 128, 1);
        mgemm_k<<<g1, block, 0, stream>>>(ts, 128, 128, S0h, S0l, 128, fs1, 64, E_EDGES);
        dim3 g2((3 * E_EDGES + 127) / 128, 1);
        mgemm_k<<<g2, block, 0, stream>>>(tv, 128, 128, V0h, V0l, 128, fv1, 64, 3 * E_EDGES);
    }

    // ---- latent update MLP + fused residual blend ----
    mgemm2(stream, 1, lat, 256, 256, ts, 128, 128, WL0h, WL0l, 384, hA, 256, E_EDGES, 256, nullptr, nullptr, nullptr, nullptr);
    mgemm2(stream, 3, hA, 256, 256, nullptr, 0, 0, WL1h, WL1l, 256, lat, 256, E_EDGES, 256, cut, res_p, nullptr, nullptr);

    // ---- stage C ----
    mgemm2(stream, 0, lat, 256, 256, nullptr, 0, 0, We1h, We1l, 256, wall, 192, E_EDGES, 192, nullptr, nullptr, nullptr, nullptr);
    envsum_k<192><<<NNODES, 64, 0, stream>>>(wall, ang, perm, offs, cnt, envlin1, ns2_e, nv2_e);
    tp1f_k<<<(E_EDGES * 64) / 256, 256, 0, stream>>>(fs1, fv1, wall, ns2_e, nv2_e, eidx, ts, tv);

    // ---- final MLP (fin) BEFORE the lin1 GEMMs so their epilogues can fuse
    //      the output assembly (out_k eliminated) ----
    mgemm2(stream, 1, lat, 256, 256, ts, 128, 128, WF0h, WF0l, 384, hA, 256, E_EDGES, 256, nullptr, nullptr, nullptr, nullptr);
    mgemm2(stream, 0, hA, 256, 256, nullptr, 0, 0, WF1h, WF1l, 256, hB, 128, E_EDGES, 128, nullptr, nullptr, nullptr, nullptr);

    // ---- lin1 GEMMs fused with output assembly ----
    // scalar half: out[e*512 + o*64+v] = acc * fin  (f32, full precision acc)
    mgemm2(stream, 4, ts, 128, 128, nullptr, 0, 0, S1h, S1l, 128, nullptr, 0, E_EDGES, 128, nullptr, nullptr, hB, (float*)d_out);
    // vector half: row=e*3+c, col=o*64+v -> out[e*512 + 128 + o*192 + v*3 + c]
    mgemm2(stream, 5, tv, 128, 128, nullptr, 0, 0, V1h, V1l, 128, nullptr, 0, 3 * E_EDGES, 128, nullptr, nullptr, nullptr, (float*)d_out);
}